// Round 1
// baseline (627.317 us; speedup 1.0000x reference)
//
#include <hip/hip_runtime.h>

#define N_ 65536
#define D_ 768
#define L_ 100
#define B_ 8192

typedef __attribute__((ext_vector_type(8))) short short8;
typedef __attribute__((ext_vector_type(4))) float floatx4;

__device__ __forceinline__ unsigned short f2bf(float f) {
    unsigned int u = __float_as_uint(f);
    u += 0x7fff + ((u >> 16) & 1);   // RNE
    return (unsigned short)(u >> 16);
}
__device__ __forceinline__ float bf2f(unsigned short u) {
    return __uint_as_float(((unsigned int)u) << 16);
}

// ---- convert h_cls f32 -> bf16, 8 elems/thread ------------------------------
__global__ __launch_bounds__(256) void conv_h_kernel(
    const float* __restrict__ src, unsigned short* __restrict__ dst)
{
    int t = blockIdx.x * 256 + threadIdx.x;      // N_*D_/8 threads exactly
    float4 a = ((const float4*)src)[2 * t];
    float4 b = ((const float4*)src)[2 * t + 1];
    uint4 o;
    o.x = (unsigned)f2bf(a.x) | ((unsigned)f2bf(a.y) << 16);
    o.y = (unsigned)f2bf(a.z) | ((unsigned)f2bf(a.w) << 16);
    o.z = (unsigned)f2bf(b.x) | ((unsigned)f2bf(b.y) << 16);
    o.w = (unsigned)f2bf(b.z) | ((unsigned)f2bf(b.w) << 16);
    ((uint4*)dst)[t] = o;
}

// ---- transpose + convert W_fc [k][n] -> Wt bf16 [n][k] ----------------------
__global__ __launch_bounds__(256) void conv_wt_kernel(
    const float* __restrict__ W, unsigned short* __restrict__ Wt)
{
    int t = blockIdx.x * 256 + threadIdx.x;
    if (t >= D_ * D_) return;
    int n = t / D_, k = t % D_;
    Wt[t] = f2bf(W[k * D_ + n]);
}

// ---- pooled = h @ W_fc + b_fc  (bf16 MFMA, 64x64 tile, stored bf16) --------
__global__ __launch_bounds__(256) void gemm_pooled(
    const unsigned short* __restrict__ A,   // h bf16 [N][D]
    const unsigned short* __restrict__ Bt,  // Wt bf16 [D(n)][D(k)]
    const float* __restrict__ bias,         // b_fc [D]
    unsigned short* __restrict__ P)         // pooled bf16 [N][D]
{
    __shared__ __align__(16) unsigned short As[64][40];  // +8 pad, 16B-aligned rows
    __shared__ __align__(16) unsigned short Bs[64][40];
    const int tid  = threadIdx.x;
    const int lane = tid & 63;
    const int wave = tid >> 6;
    const int l15  = lane & 15;
    const int quad = lane >> 4;
    const int mBase = blockIdx.y * 64;
    const int nBase = blockIdx.x * 64;
    const int srow = tid >> 2;        // 0..63
    const int skc  = (tid & 3) * 8;   // 0,8,16,24

    floatx4 acc[4];
#pragma unroll
    for (int nt = 0; nt < 4; ++nt) acc[nt] = (floatx4){0.f, 0.f, 0.f, 0.f};

    for (int k0 = 0; k0 < D_; k0 += 32) {
        __syncthreads();
        *(uint4*)&As[srow][skc] =
            *(const uint4*)&A[(size_t)(mBase + srow) * D_ + k0 + skc];
        *(uint4*)&Bs[srow][skc] =
            *(const uint4*)&Bt[(size_t)(nBase + srow) * D_ + k0 + skc];
        __syncthreads();
        short8 af = *(const short8*)&As[wave * 16 + l15][quad * 8];
#pragma unroll
        for (int nt = 0; nt < 4; ++nt) {
            short8 bf = *(const short8*)&Bs[nt * 16 + l15][quad * 8];
            acc[nt] = __builtin_amdgcn_mfma_f32_16x16x32_bf16(af, bf, acc[nt], 0, 0, 0);
        }
    }
    // C/D layout: col = lane&15, row = quad*4 + reg  [m89/m91 verified]
#pragma unroll
    for (int nt = 0; nt < 4; ++nt) {
        int col = nBase + nt * 16 + l15;
        float bv = bias[col];
#pragma unroll
        for (int r = 0; r < 4; ++r) {
            int row = mBase + wave * 16 + quad * 4 + r;
            P[(size_t)row * D_ + col] = f2bf(acc[nt][r] + bv);
        }
    }
}

// ---- logit[i] = dot(att_weight[query[i]], pooled[i]) — one wave / sentence --
__global__ __launch_bounds__(256) void logit_kernel(
    const unsigned short* __restrict__ P, const float* __restrict__ att,
    const int* __restrict__ query, float* __restrict__ logit)
{
    int gw   = (blockIdx.x * 256 + threadIdx.x) >> 6;  // sentence id
    int lane = threadIdx.x & 63;
    int q = query[gw];
    const unsigned short* prow = P + (size_t)gw * D_;
    const float* arow = att + (size_t)q * D_;
    float dot = 0.f;
#pragma unroll
    for (int c = 0; c < 3; ++c) {
        int idx = c * 256 + lane * 4;
        ushort4 pb = *(const ushort4*)(prow + idx);
        float4  av = *(const float4*)(arow + idx);
        dot += bf2f(pb.x) * av.x + bf2f(pb.y) * av.y
             + bf2f(pb.z) * av.z + bf2f(pb.w) * av.w;
    }
#pragma unroll
    for (int off = 32; off > 0; off >>= 1) dot += __shfl_down(dot, off, 64);
    if (lane == 0) logit[gw] = dot;
}

// ---- bag start offsets via lower_bound (seg_ids sorted; empties handled) ----
__global__ __launch_bounds__(256) void seg_offsets_kernel(
    const int* __restrict__ seg, int* __restrict__ start)
{
    int b = blockIdx.x * 256 + threadIdx.x;
    if (b > B_) return;
    int lo = 0, hi = N_;
    while (lo < hi) {
        int mid = (lo + hi) >> 1;
        if (seg[mid] < b) lo = mid + 1; else hi = mid;
    }
    start[b] = lo;
}

// ---- per-bag softmax + weighted sum of pooled rows --------------------------
__global__ __launch_bounds__(256) void bag_kernel(
    const unsigned short* __restrict__ P, const float* __restrict__ logit,
    const int* __restrict__ start, float* __restrict__ R)
{
    int b = blockIdx.x;
    int s = start[b], e = start[b + 1];
    int tid = threadIdx.x;
    __shared__ float sdata[256];

    float m = -INFINITY;
    for (int i = s + tid; i < e; i += 256) m = fmaxf(m, logit[i]);
    sdata[tid] = m;
    __syncthreads();
    for (int off = 128; off > 0; off >>= 1) {
        if (tid < off) sdata[tid] = fmaxf(sdata[tid], sdata[tid + off]);
        __syncthreads();
    }
    m = sdata[0];
    __syncthreads();

    float zz = 0.f;
    for (int i = s + tid; i < e; i += 256) zz += expf(logit[i] - m);
    sdata[tid] = zz;
    __syncthreads();
    for (int off = 128; off > 0; off >>= 1) {
        if (tid < off) sdata[tid] += sdata[tid + off];
        __syncthreads();
    }
    float z = sdata[0];

    float a0 = 0.f, a1 = 0.f, a2 = 0.f;
    for (int i = s; i < e; ++i) {
        float w = expf(logit[i] - m) / z;     // uniform across block
        const unsigned short* row = P + (size_t)i * D_;
        a0 += w * bf2f(row[tid]);
        a1 += w * bf2f(row[tid + 256]);
        a2 += w * bf2f(row[tid + 512]);
    }
    float* o = R + (size_t)b * D_;
    o[tid] = a0; o[tid + 256] = a1; o[tid + 512] = a2;   // empty bag -> zeros
}

// ---- logits = bag_repre @ W_cls + b_cls  (16 bags / block) ------------------
__global__ __launch_bounds__(128) void cls_kernel(
    const float* __restrict__ R, const float* __restrict__ Wc,
    const float* __restrict__ bc, float* __restrict__ out)
{
    __shared__ float sm[16 * D_];
    int b0 = blockIdx.x * 16;
    int tid = threadIdx.x;
    const float* src = R + (size_t)b0 * D_;
    for (int idx = tid; idx < 16 * D_; idx += 128) sm[idx] = src[idx];
    __syncthreads();
    if (tid < L_) {
        float acc[16];
#pragma unroll
        for (int j = 0; j < 16; ++j) acc[j] = 0.f;
        for (int d = 0; d < D_; ++d) {
            float wv = Wc[d * L_ + tid];
#pragma unroll
            for (int j = 0; j < 16; ++j) acc[j] += sm[j * D_ + d] * wv;
        }
        float bias = bc[tid];
#pragma unroll
        for (int j = 0; j < 16; ++j)
            out[(size_t)(b0 + j) * L_ + tid] = acc[j] + bias;
    }
}

extern "C" void kernel_launch(void* const* d_in, const int* in_sizes, int n_in,
                              void* d_out, int out_size, void* d_ws, size_t ws_size,
                              hipStream_t stream) {
    const float* h    = (const float*)d_in[0];
    const float* Wfc  = (const float*)d_in[1];
    const float* bfc  = (const float*)d_in[2];
    const float* att  = (const float*)d_in[3];
    const float* Wcls = (const float*)d_in[4];
    const float* bcls = (const float*)d_in[5];
    const int*   query= (const int*)d_in[6];
    const int*   seg  = (const int*)d_in[7];
    float* out = (float*)d_out;

    char* w = (char*)d_ws;
    unsigned short* h_bf   = (unsigned short*)w;  w += (size_t)N_ * D_ * 2;
    unsigned short* Wt     = (unsigned short*)w;  w += (size_t)D_ * D_ * 2;
    unsigned short* pooled = (unsigned short*)w;  w += (size_t)N_ * D_ * 2;
    float* logit           = (float*)w;           w += (size_t)N_ * 4;
    int*   start           = (int*)w;             w += (((B_ + 1) * 4 + 127) & ~127);
    float* repre           = (float*)w;           // B_*D_*4

    conv_h_kernel     <<<N_ * D_ / 8 / 256, 256, 0, stream>>>(h, h_bf);
    conv_wt_kernel    <<<(D_ * D_ + 255) / 256, 256, 0, stream>>>(Wfc, Wt);
    gemm_pooled       <<<dim3(D_ / 64, N_ / 64), 256, 0, stream>>>(h_bf, Wt, bfc, pooled);
    logit_kernel      <<<N_ / 4, 256, 0, stream>>>(pooled, att, query, logit);
    seg_offsets_kernel<<<(B_ + 1 + 255) / 256, 256, 0, stream>>>(seg, start);
    bag_kernel        <<<B_, 256, 0, stream>>>(pooled, logit, start, repre);
    cls_kernel        <<<B_ / 16, 128, 0, stream>>>(repre, Wcls, bcls, out);
}

// Round 2
// 481.600 us; speedup vs baseline: 1.3026x; 1.3026x over previous
//
#include <hip/hip_runtime.h>

#define N_ 65536
#define D_ 768
#define L_ 100
#define B_ 8192

typedef __attribute__((ext_vector_type(8))) short short8;
typedef __attribute__((ext_vector_type(4))) float floatx4;

__device__ __forceinline__ unsigned short f2bf(float f) {
    unsigned int u = __float_as_uint(f);
    u += 0x7fff + ((u >> 16) & 1);   // RNE
    return (unsigned short)(u >> 16);
}
__device__ __forceinline__ float bf2f(unsigned short u) {
    return __uint_as_float(((unsigned int)u) << 16);
}

// async global->LDS, 16B per lane; lds dest must be wave-uniform base (lane*16 implicit)
__device__ __forceinline__ void gload16(const unsigned short* g, unsigned short* l) {
    __builtin_amdgcn_global_load_lds(
        (const __attribute__((address_space(1))) void*)g,
        (__attribute__((address_space(3))) void*)l, 16, 0, 0);
}

// ---- convert h_cls f32 -> bf16, 8 elems/thread ------------------------------
__global__ __launch_bounds__(256) void conv_h_kernel(
    const float* __restrict__ src, unsigned short* __restrict__ dst)
{
    int t = blockIdx.x * 256 + threadIdx.x;      // N_*D_/8 threads exactly
    float4 a = ((const float4*)src)[2 * t];
    float4 b = ((const float4*)src)[2 * t + 1];
    uint4 o;
    o.x = (unsigned)f2bf(a.x) | ((unsigned)f2bf(a.y) << 16);
    o.y = (unsigned)f2bf(a.z) | ((unsigned)f2bf(a.w) << 16);
    o.z = (unsigned)f2bf(b.x) | ((unsigned)f2bf(b.y) << 16);
    o.w = (unsigned)f2bf(b.z) | ((unsigned)f2bf(b.w) << 16);
    ((uint4*)dst)[t] = o;
}

// ---- transpose + convert W_fc [k][n] -> Wt bf16 [n][k] ----------------------
__global__ __launch_bounds__(256) void conv_wt_kernel(
    const float* __restrict__ W, unsigned short* __restrict__ Wt)
{
    int t = blockIdx.x * 256 + threadIdx.x;
    if (t >= D_ * D_) return;
    int n = t / D_, k = t % D_;
    Wt[t] = f2bf(W[k * D_ + n]);
}

// ---- transpose + convert + pad W_cls [k][l] -> Wct bf16 [128][768] ----------
__global__ __launch_bounds__(256) void conv_wct_kernel(
    const float* __restrict__ W, unsigned short* __restrict__ Wt)
{
    int t = blockIdx.x * 256 + threadIdx.x;
    if (t >= 128 * D_) return;
    int n = t / D_, k = t % D_;
    Wt[t] = (n < L_) ? f2bf(W[k * L_ + n]) : (unsigned short)0;
}

// ---- pooled = h @ W_fc + b_fc  (m97 structure: 128x128 tile, global_load_lds)
__global__ __launch_bounds__(256) void gemm_pooled(
    const unsigned short* __restrict__ A,   // h bf16 [N][768]
    const unsigned short* __restrict__ Bt,  // Wt bf16 [768(n)][768(k)]
    const float* __restrict__ bias,         // b_fc
    unsigned short* __restrict__ P)         // pooled bf16 [N][768]
{
    __shared__ __align__(16) unsigned short As[128 * 32];  // [row][k] 64B rows, NO pad
    __shared__ __align__(16) unsigned short Bs[128 * 32];
    const int tid  = threadIdx.x;
    const int lane = tid & 63;
    const int wave = tid >> 6;
    const int l15  = lane & 15;
    const int quad = lane >> 4;
    const int wm   = wave >> 1, wn = wave & 1;
    const size_t mBase = (size_t)blockIdx.y * 128;
    const size_t nBase = (size_t)blockIdx.x * 128;

    // staging: 512 chunks of 16B per matrix; wave w covers [w*128, w*128+128)
    const int c0 = wave * 128 + lane;
    const int c1 = c0 + 64;
    const int r0 = c0 >> 2, s0 = (c0 & 3) * 8;
    const int r1 = c1 >> 2, s1 = (c1 & 3) * 8;
    unsigned short* ldsA0 = As + wave * 1024;
    unsigned short* ldsA1 = As + wave * 1024 + 512;
    unsigned short* ldsB0 = Bs + wave * 1024;
    unsigned short* ldsB1 = Bs + wave * 1024 + 512;
    const unsigned short* gA0 = A  + (mBase + r0) * D_ + s0;
    const unsigned short* gA1 = A  + (mBase + r1) * D_ + s1;
    const unsigned short* gB0 = Bt + (nBase + r0) * D_ + s0;
    const unsigned short* gB1 = Bt + (nBase + r1) * D_ + s1;

    floatx4 acc[4][4];
#pragma unroll
    for (int mi = 0; mi < 4; ++mi)
#pragma unroll
        for (int ni = 0; ni < 4; ++ni) acc[mi][ni] = (floatx4){0.f, 0.f, 0.f, 0.f};

    for (int k0 = 0; k0 < D_; k0 += 32) {
        __syncthreads();
        gload16(gA0 + k0, ldsA0);
        gload16(gA1 + k0, ldsA1);
        gload16(gB0 + k0, ldsB0);
        gload16(gB1 + k0, ldsB1);
        __syncthreads();
        short8 af[4], bfr[4];
#pragma unroll
        for (int mi = 0; mi < 4; ++mi)
            af[mi] = *(const short8*)&As[(wm * 64 + mi * 16 + l15) * 32 + quad * 8];
#pragma unroll
        for (int ni = 0; ni < 4; ++ni)
            bfr[ni] = *(const short8*)&Bs[(wn * 64 + ni * 16 + l15) * 32 + quad * 8];
#pragma unroll
        for (int mi = 0; mi < 4; ++mi)
#pragma unroll
            for (int ni = 0; ni < 4; ++ni)
                acc[mi][ni] = __builtin_amdgcn_mfma_f32_16x16x32_bf16(
                    af[mi], bfr[ni], acc[mi][ni], 0, 0, 0);
    }
    // C/D: col = lane&15, row = quad*4 + reg
#pragma unroll
    for (int ni = 0; ni < 4; ++ni) {
        int col = (int)nBase + wn * 64 + ni * 16 + l15;
        float bv = bias[col];
#pragma unroll
        for (int mi = 0; mi < 4; ++mi)
#pragma unroll
            for (int r = 0; r < 4; ++r) {
                size_t row = mBase + wm * 64 + mi * 16 + quad * 4 + r;
                P[row * D_ + col] = f2bf(acc[mi][ni][r] + bv);
            }
    }
}

// ---- logits = bag_repre(bf16) @ Wct^T + b_cls  (same m97 body, N padded 128) -
__global__ __launch_bounds__(256) void gemm_cls(
    const unsigned short* __restrict__ A,   // repre bf16 [B_][768]
    const unsigned short* __restrict__ Bt,  // Wct bf16 [128][768]
    const float* __restrict__ bias,         // b_cls [100]
    float* __restrict__ out)                // [B_][100] f32
{
    __shared__ __align__(16) unsigned short As[128 * 32];
    __shared__ __align__(16) unsigned short Bs[128 * 32];
    const int tid  = threadIdx.x;
    const int lane = tid & 63;
    const int wave = tid >> 6;
    const int l15  = lane & 15;
    const int quad = lane >> 4;
    const int wm   = wave >> 1, wn = wave & 1;
    const size_t mBase = (size_t)blockIdx.y * 128;

    const int c0 = wave * 128 + lane;
    const int c1 = c0 + 64;
    const int r0 = c0 >> 2, s0 = (c0 & 3) * 8;
    const int r1 = c1 >> 2, s1 = (c1 & 3) * 8;
    unsigned short* ldsA0 = As + wave * 1024;
    unsigned short* ldsA1 = As + wave * 1024 + 512;
    unsigned short* ldsB0 = Bs + wave * 1024;
    unsigned short* ldsB1 = Bs + wave * 1024 + 512;
    const unsigned short* gA0 = A  + (mBase + r0) * D_ + s0;
    const unsigned short* gA1 = A  + (mBase + r1) * D_ + s1;
    const unsigned short* gB0 = Bt + (size_t)r0 * D_ + s0;
    const unsigned short* gB1 = Bt + (size_t)r1 * D_ + s1;

    floatx4 acc[4][4];
#pragma unroll
    for (int mi = 0; mi < 4; ++mi)
#pragma unroll
        for (int ni = 0; ni < 4; ++ni) acc[mi][ni] = (floatx4){0.f, 0.f, 0.f, 0.f};

    for (int k0 = 0; k0 < D_; k0 += 32) {
        __syncthreads();
        gload16(gA0 + k0, ldsA0);
        gload16(gA1 + k0, ldsA1);
        gload16(gB0 + k0, ldsB0);
        gload16(gB1 + k0, ldsB1);
        __syncthreads();
        short8 af[4], bfr[4];
#pragma unroll
        for (int mi = 0; mi < 4; ++mi)
            af[mi] = *(const short8*)&As[(wm * 64 + mi * 16 + l15) * 32 + quad * 8];
#pragma unroll
        for (int ni = 0; ni < 4; ++ni)
            bfr[ni] = *(const short8*)&Bs[(wn * 64 + ni * 16 + l15) * 32 + quad * 8];
#pragma unroll
        for (int mi = 0; mi < 4; ++mi)
#pragma unroll
            for (int ni = 0; ni < 4; ++ni)
                acc[mi][ni] = __builtin_amdgcn_mfma_f32_16x16x32_bf16(
                    af[mi], bfr[ni], acc[mi][ni], 0, 0, 0);
    }
#pragma unroll
    for (int ni = 0; ni < 4; ++ni) {
        int col = wn * 64 + ni * 16 + l15;
        if (col < L_) {
            float bv = bias[col];
#pragma unroll
            for (int mi = 0; mi < 4; ++mi)
#pragma unroll
                for (int r = 0; r < 4; ++r) {
                    size_t row = mBase + wm * 64 + mi * 16 + quad * 4 + r;
                    out[row * L_ + col] = acc[mi][ni][r] + bv;
                }
        }
    }
}

// ---- logit[i] = dot(att_weight[query[i]], pooled[i]) — one wave / sentence --
__global__ __launch_bounds__(256) void logit_kernel(
    const unsigned short* __restrict__ P, const float* __restrict__ att,
    const int* __restrict__ query, float* __restrict__ logit)
{
    int gw   = (blockIdx.x * 256 + threadIdx.x) >> 6;  // sentence id
    int lane = threadIdx.x & 63;
    int q = query[gw];
    const unsigned short* prow = P + (size_t)gw * D_;
    const float* arow = att + (size_t)q * D_;
    float dot = 0.f;
#pragma unroll
    for (int c = 0; c < 3; ++c) {
        int idx = c * 256 + lane * 4;
        ushort4 pb = *(const ushort4*)(prow + idx);
        float4  av = *(const float4*)(arow + idx);
        dot += bf2f(pb.x) * av.x + bf2f(pb.y) * av.y
             + bf2f(pb.z) * av.z + bf2f(pb.w) * av.w;
    }
#pragma unroll
    for (int off = 32; off > 0; off >>= 1) dot += __shfl_down(dot, off, 64);
    if (lane == 0) logit[gw] = dot;
}

// ---- bag start offsets via lower_bound (seg_ids sorted; empties handled) ----
__global__ __launch_bounds__(256) void seg_offsets_kernel(
    const int* __restrict__ seg, int* __restrict__ start)
{
    int b = blockIdx.x * 256 + threadIdx.x;
    if (b > B_) return;
    int lo = 0, hi = N_;
    while (lo < hi) {
        int mid = (lo + hi) >> 1;
        if (seg[mid] < b) lo = mid + 1; else hi = mid;
    }
    start[b] = lo;
}

// ---- per-bag softmax + weighted sum: ONE WAVE per bag, no barriers ----------
__global__ __launch_bounds__(256) void bag_kernel(
    const unsigned short* __restrict__ P, const float* __restrict__ logit,
    const int* __restrict__ start, unsigned short* __restrict__ R)
{
    int b    = blockIdx.x * 4 + (threadIdx.x >> 6);
    int lane = threadIdx.x & 63;
    int s = start[b], e = start[b + 1];

    float m = -INFINITY;
    for (int i = s + lane; i < e; i += 64) m = fmaxf(m, logit[i]);
#pragma unroll
    for (int off = 32; off > 0; off >>= 1) m = fmaxf(m, __shfl_xor(m, off, 64));

    float z = 0.f;
    for (int i = s + lane; i < e; i += 64) z += expf(logit[i] - m);
#pragma unroll
    for (int off = 32; off > 0; off >>= 1) z += __shfl_xor(z, off, 64);
    float invz = (e > s) ? 1.f / z : 0.f;

    float acc[12];
#pragma unroll
    for (int j = 0; j < 12; ++j) acc[j] = 0.f;
    for (int i = s; i < e; ++i) {
        float w = expf(logit[i] - m) * invz;   // uniform across wave
        const unsigned short* row = P + (size_t)i * D_;
#pragma unroll
        for (int j = 0; j < 12; ++j) acc[j] += w * bf2f(row[lane + j * 64]);
    }
    unsigned short* o = R + (size_t)b * D_;
#pragma unroll
    for (int j = 0; j < 12; ++j) o[lane + j * 64] = f2bf(acc[j]);
}

extern "C" void kernel_launch(void* const* d_in, const int* in_sizes, int n_in,
                              void* d_out, int out_size, void* d_ws, size_t ws_size,
                              hipStream_t stream) {
    const float* h    = (const float*)d_in[0];
    const float* Wfc  = (const float*)d_in[1];
    const float* bfc  = (const float*)d_in[2];
    const float* att  = (const float*)d_in[3];
    const float* Wcls = (const float*)d_in[4];
    const float* bcls = (const float*)d_in[5];
    const int*   query= (const int*)d_in[6];
    const int*   seg  = (const int*)d_in[7];
    float* out = (float*)d_out;

    char* w = (char*)d_ws;
    unsigned short* h_bf   = (unsigned short*)w;  w += (size_t)N_ * D_ * 2;
    unsigned short* Wt     = (unsigned short*)w;  w += (size_t)D_ * D_ * 2;
    unsigned short* Wct    = (unsigned short*)w;  w += (size_t)128 * D_ * 2;
    unsigned short* pooled = (unsigned short*)w;  w += (size_t)N_ * D_ * 2;
    float* logit           = (float*)w;           w += (size_t)N_ * 4;
    int*   start           = (int*)w;             w += (((B_ + 1) * 4 + 127) & ~127);
    unsigned short* repre  = (unsigned short*)w;  // B_*D_*2

    conv_h_kernel     <<<N_ * D_ / 8 / 256, 256, 0, stream>>>(h, h_bf);
    conv_wt_kernel    <<<(D_ * D_ + 255) / 256, 256, 0, stream>>>(Wfc, Wt);
    conv_wct_kernel   <<<(128 * D_ + 255) / 256, 256, 0, stream>>>(Wcls, Wct);
    gemm_pooled       <<<dim3(D_ / 128, N_ / 128), 256, 0, stream>>>(h_bf, Wt, bfc, pooled);
    logit_kernel      <<<N_ / 4, 256, 0, stream>>>(pooled, att, query, logit);
    seg_offsets_kernel<<<(B_ + 1 + 255) / 256, 256, 0, stream>>>(seg, start);
    bag_kernel        <<<B_ / 4, 256, 0, stream>>>(pooled, logit, start, repre);
    gemm_cls          <<<dim3(1, B_ / 128), 256, 0, stream>>>(repre, Wct, bcls, out);
}